// Round 3
// baseline (10.125 us; speedup 1.0000x reference)
//
#include <hip/hip_runtime.h>

// B=32, N=64, T=50, F=2, E=8. Only node 0 of each (b,t) graph matters.
// out[0:3200)     = x[:,0]       (B,T,F)
// out[3200:16000) = enc[:,:,0,:] (B,T,E)
//
// Block = 256 threads = 4 waves per graph. Thread (n = tid&63, s = tid>>6):
// slice s computes deg-partial of node n over neighbors k in [16s, 16s+16).
// Self-term w(n,n)=min(rsq(0),1)=1 supplies the reference's "+1" exactly once.
// Wave 0 then combines degrees and does the node-0 aggregation (F=2 collapses
// the 63-neighbor sum to two scalars sum(c*px), sum(c*py)).

__global__ __launch_bounds__(256) void encoder_spatial_kernel(
    const float* __restrict__ x,      // (B,N,T,F)
    const float* __restrict__ W_res,  // (2,8)
    const float* __restrict__ W_gcn,  // (2,8)
    const float* __restrict__ b_gcn,  // (8,)
    float* __restrict__ out)          // 16000 floats
{
    constexpr int N = 64, T = 50, F = 2, E = 8;
    const int g = blockIdx.x;         // b*T + t
    const int b = g / T;
    const int t = g % T;
    const int n = threadIdx.x & 63;   // node
    const int s = threadIdx.x >> 6;   // neighbor slice 0..3

    __shared__ float2 sp[64];
    __shared__ float  sdeg[4][64];

    // wave 0 stages positions (x[b, n, t, 0:2], 8B aligned)
    if (s == 0) {
        sp[n] = *reinterpret_cast<const float2*>(
            x + ((size_t)(b * N + n) * T + t) * F);
    }
    __syncthreads();

    const float2 p = sp[n];

    // partial degree over this slice's 16 neighbors; slice 0 captures w(n,0)
    float deg = 0.0f;
    float w0  = 0.0f;
    const int k0 = s * 16;
    #pragma unroll
    for (int j = 0; j < 16; ++j) {
        const float2 q = sp[k0 + j];
        const float dx = p.x - q.x;
        const float dy = p.y - q.y;
        const float d2 = dx * dx + dy * dy;
        const float w  = fminf(__builtin_amdgcn_rsqf(d2), 1.0f); // rsq(0)=inf -> 1
        deg += w;
        if (k0 + j == 0) w0 = w;      // compile-time: only slice 0, j==0
    }
    sdeg[s][n] = deg;
    __syncthreads();

    if (s != 0) return;               // after the barrier: safe

    // wave 0: full degree, dinv, then node-0 aggregation
    const float degf = sdeg[0][n] + sdeg[1][n] + sdeg[2][n] + sdeg[3][n];
    const float dinv = __builtin_amdgcn_rsqf(degf);   // deg >= 1

    const float c = (n == 0) ? 0.0f : dinv * w0;      // dinv_n * w(n,0)
    float cx = c * p.x;
    float cy = c * p.y;
    #pragma unroll
    for (int off = 32; off > 0; off >>= 1) {
        cx += __shfl_xor(cx, off, 64);
        cy += __shfl_xor(cy, off, 64);
    }

    const float dinv0 = __shfl(dinv, 0, 64);
    const float px0 = sp[0].x;
    const float py0 = sp[0].y;

    if (n < E) {
        const float wg0 = W_gcn[n];
        const float wg1 = W_gcn[E + n];
        float agg = dinv0 * (cx * wg0 + cy * wg1)
                  + dinv0 * dinv0 * (px0 * wg0 + py0 * wg1);
        float enc = agg + b_gcn[n] + px0 * W_res[n] + py0 * W_res[E + n];
        out[3200 + g * E + n] = fmaxf(enc, 0.0f);
    }
    if (n < F) {
        out[g * F + n] = (n == 0) ? px0 : py0;
    }
}

extern "C" void kernel_launch(void* const* d_in, const int* in_sizes, int n_in,
                              void* d_out, int out_size, void* d_ws, size_t ws_size,
                              hipStream_t stream) {
    const float* x     = (const float*)d_in[0];
    const float* W_res = (const float*)d_in[1];
    const float* W_gcn = (const float*)d_in[2];
    const float* b_gcn = (const float*)d_in[3];
    float* out = (float*)d_out;

    encoder_spatial_kernel<<<32 * 50, 256, 0, stream>>>(x, W_res, W_gcn, b_gcn, out);
}

// Round 4
// 9.647 us; speedup vs baseline: 1.0495x; 1.0495x over previous
//
#include <hip/hip_runtime.h>

// B=32, N=64, T=50, F=2, E=8. Only node 0 of each (b,t) graph matters.
// out[0:3200)     = x[:,0]       (B,T,F)
// out[3200:16000) = enc[:,:,0,:] (B,T,E)
//
// Block = 512 threads = 8 waves, handles 8 consecutive graphs g0..g0+7.
// Cooperative coalesced load: thread i -> (n = i>>3, j = i&7) loads
// x[b_j, n, t_j, 0:2]; 8 consecutive threads cover 64 contiguous bytes.
// Then wave j independently processes graph g0+j entirely from LDS.

__global__ __launch_bounds__(512) void encoder_spatial_kernel(
    const float* __restrict__ x,      // (B,N,T,F)
    const float* __restrict__ W_res,  // (2,8)
    const float* __restrict__ W_gcn,  // (2,8)
    const float* __restrict__ b_gcn,  // (8,)
    float* __restrict__ out)          // 16000 floats
{
    constexpr int N = 64, T = 50, F = 2, E = 8;
    const int g0 = blockIdx.x * 8;

    __shared__ float2 sp[8][65];      // [graph j][node n], +1 pad vs write conflicts

    {
        const int i = threadIdx.x;
        const int n = i >> 3;
        const int j = i & 7;
        const int g = g0 + j;
        const int b = g / T;
        const int t = g % T;
        sp[j][n] = *reinterpret_cast<const float2*>(
            x + ((size_t)(b * N + n) * T + t) * F);
    }
    __syncthreads();

    const int j    = threadIdx.x >> 6;   // wave id = local graph
    const int lane = threadIdx.x & 63;   // node
    const int g    = g0 + j;

    const float2 p = sp[j][lane];

    // degree with 4 accumulators (break serial FP chain); self-term k==lane
    // gives w=min(rsq(0),1)=1 == the reference's "+1". Capture w(lane,0).
    float d0 = 0.f, d1 = 0.f, d2a = 0.f, d3 = 0.f;
    float w0 = 0.f;
    #pragma unroll
    for (int k = 0; k < 64; k += 4) {
        #pragma unroll
        for (int u = 0; u < 4; ++u) {
            const float2 q = sp[j][k + u];
            const float dx = p.x - q.x;
            const float dy = p.y - q.y;
            const float w  = fminf(__builtin_amdgcn_rsqf(dx * dx + dy * dy), 1.0f);
            if (k + u == 0) { w0 = w; d0 += w; }
            else if (u == 0) d0 += w;
            else if (u == 1) d1 += w;
            else if (u == 2) d2a += w;
            else             d3 += w;
        }
    }
    const float deg  = (d0 + d1) + (d2a + d3);
    const float dinv = __builtin_amdgcn_rsqf(deg);   // deg >= 1

    // c_i = dinv_i * w(i,0) (0 for i==0); reduce sum(c*px), sum(c*py)
    const float c = (lane == 0) ? 0.0f : dinv * w0;
    float cx = c * p.x;
    float cy = c * p.y;
    #pragma unroll
    for (int off = 32; off > 0; off >>= 1) {
        cx += __shfl_xor(cx, off, 64);
        cy += __shfl_xor(cy, off, 64);
    }

    const float dinv0 = __shfl(dinv, 0, 64);
    const float px0 = sp[j][0].x;
    const float py0 = sp[j][0].y;

    if (lane < E) {
        const float wg0 = W_gcn[lane];
        const float wg1 = W_gcn[E + lane];
        float agg = dinv0 * (cx * wg0 + cy * wg1)
                  + dinv0 * dinv0 * (px0 * wg0 + py0 * wg1);
        float enc = agg + b_gcn[lane] + px0 * W_res[lane] + py0 * W_res[E + lane];
        out[3200 + g * E + lane] = fmaxf(enc, 0.0f);
    }
    if (lane < F) {
        out[g * F + lane] = (lane == 0) ? px0 : py0;
    }
}

extern "C" void kernel_launch(void* const* d_in, const int* in_sizes, int n_in,
                              void* d_out, int out_size, void* d_ws, size_t ws_size,
                              hipStream_t stream) {
    const float* x     = (const float*)d_in[0];
    const float* W_res = (const float*)d_in[1];
    const float* W_gcn = (const float*)d_in[2];
    const float* b_gcn = (const float*)d_in[3];
    float* out = (float*)d_out;

    // 1600 graphs / 8 per block = 200 blocks
    encoder_spatial_kernel<<<200, 512, 0, stream>>>(x, W_res, W_gcn, b_gcn, out);
}